// Round 6
// baseline (1135.197 us; speedup 1.0000x reference)
//
#include <hip/hip_runtime.h>
#include <hip/hip_bf16.h>

typedef __hip_bfloat16 bf16;
using bf16x8 = __attribute__((ext_vector_type(8))) __bf16;
using f32x4  = __attribute__((ext_vector_type(4))) float;

#define S_   2048
#define D_   2048
#define H_   16
#define QR_  1536
#define KVR_ 512
#define NOPE_ 128
#define ROPE_ 64
#define VD_  128
#define QKD_ 192
#define EPS_ 1e-5f
#define QKVN 2112   // QR_ + KVR_ + ROPE_ (fused qa+kva output width)

// async global->LDS, 16B per lane; LDS dest = wave-uniform base + lane*16
#define GLDS16(g, l) \
    __builtin_amdgcn_global_load_lds((const __attribute__((address_space(1))) void*)(g), \
                                     (__attribute__((address_space(3))) void*)(l), 16, 0, 0)

// ---------------------------------------------------------------------------
// bf16 MFMA GEMM: C[M,N] = A[M,K] @ B[K,N], B given as BT[N,K].
// 256 thr = 4 waves; tile 128x128; wave does 64x64 (4x4 of 16x16x32 bf16).
// Double-buffered single-barrier K-loop (prefetch overlaps MFMAs) + split-K:
// chunk kc writes its own f32 partial plane (mode 6) at bzC*strideC; a reduce
// kernel sums planes and applies the epilogue. No atomics.
// mode: 0=f32 store, 1=bf16 store, 2=f32 +res, 3=bf16 gelu(x+bias),
//       4=f32 +bias+res, 6=f32 partial store (split-K)
// causal: 0=none, 1=skip tiles above diagonal (scores), 2=K limited to diag (PV)
// ---------------------------------------------------------------------------
__global__ __launch_bounds__(256) void gemm_k(
    const bf16* __restrict__ A, const bf16* __restrict__ BT, void* __restrict__ Cv,
    const float* __restrict__ bias, const float* __restrict__ res,
    int M, int N, int K, int lda, int ldb, int ldc,
    long long strideA, long long strideB, long long strideC,
    int mode, int causal, int ksplit, int kchunk)
{
    int bn = blockIdx.x, bm = blockIdx.y;
    int bzC = blockIdx.z;                 // C-plane index (batch*ksplit packed)
    int bz = bzC, kc = 0;
    if (ksplit > 1) { kc = bzC % ksplit; bz = bzC / ksplit; }
    if (causal == 1 && bn > bm) return;
    A  += (size_t)bz * strideA;
    BT += (size_t)bz * strideB;

    int k_end = K;
    if (causal == 2) { int kl = (bm + 1) * 128; if (kl < k_end) k_end = kl; }
    int k_begin = kc * kchunk;
    if (k_begin + kchunk < k_end) k_end = k_begin + kchunk;
    if (k_begin >= k_end) return;
    int nIter = (k_end - k_begin) >> 5;   // K multiples of 32 everywhere here

    __shared__ bf16 sA[2 * 128 * 32];
    __shared__ bf16 sB[2 * 128 * 32];

    int tid  = threadIdx.x;
    int lane = tid & 63, wave = tid >> 6;
    int wr = wave >> 1, wc = wave & 1;     // wave's 64x64 quadrant
    int fr = lane & 15, fq = lane >> 4;    // fragment row / k-quad

    int row0 = bm * 128, col0 = bn * 128;

    // staging: wave w covers rows [w*16, w*16+16) and +64; lane L -> row w*16+L/4, k-off (L&3)*8
    int srow = wave * 16 + (lane >> 2);
    int sko  = (lane & 3) * 8;
    const bf16* ga0 = A + (size_t)(row0 + srow) * lda + sko;
    const bf16* ga1 = ga0 + (size_t)64 * lda;
    int bn0 = col0 + srow;      if (bn0 > N - 1) bn0 = N - 1;   // clamp (cols >= N discarded)
    int bn1 = col0 + srow + 64; if (bn1 > N - 1) bn1 = N - 1;
    const bf16* gb0 = BT + (size_t)bn0 * ldb + sko;
    const bf16* gb1 = BT + (size_t)bn1 * ldb + sko;
    bf16* lA0 = &sA[(wave * 16) * 32];
    bf16* lA1 = &sA[(64 + wave * 16) * 32];
    bf16* lB0 = &sB[(wave * 16) * 32];
    bf16* lB1 = &sB[(64 + wave * 16) * 32];

#define STAGE(buf, k0) do {                       \
        GLDS16(ga0 + (k0), lA0 + (buf) * 4096);   \
        GLDS16(ga1 + (k0), lA1 + (buf) * 4096);   \
        GLDS16(gb0 + (k0), lB0 + (buf) * 4096);   \
        GLDS16(gb1 + (k0), lB1 + (buf) * 4096);   \
    } while (0)

    f32x4 acc[4][4] = {};

#define COMPUTE(buf) do {                                                           \
        bf16x8 af[4], bv[4];                                                        \
        _Pragma("unroll")                                                           \
        for (int i = 0; i < 4; ++i)                                                 \
            af[i] = *(const bf16x8*)&sA[(buf)*4096 + (wr*64 + i*16 + fr)*32 + fq*8];\
        _Pragma("unroll")                                                           \
        for (int j = 0; j < 4; ++j)                                                 \
            bv[j] = *(const bf16x8*)&sB[(buf)*4096 + (wc*64 + j*16 + fr)*32 + fq*8];\
        _Pragma("unroll")                                                           \
        for (int i = 0; i < 4; ++i)                                                 \
            _Pragma("unroll")                                                       \
            for (int j = 0; j < 4; ++j)                                             \
                acc[i][j] = __builtin_amdgcn_mfma_f32_16x16x32_bf16(af[i], bv[j], acc[i][j], 0, 0, 0); \
    } while (0)

    STAGE(0, k_begin);
    for (int it = 0; it < nIter; it += 2) {
        __syncthreads();                                          // drains stage(it)
        if (it + 1 < nIter) STAGE(1, k_begin + (it + 1) * 32);    // prefetch overlaps MFMAs
        COMPUTE(0);
        if (it + 1 < nIter) {
            __syncthreads();                                      // drains stage(it+1)
            if (it + 2 < nIter) STAGE(0, k_begin + (it + 2) * 32);
            COMPUTE(1);
        }
    }
#undef STAGE
#undef COMPUTE

    // epilogue: D[row=(lane>>4)*4+r][col=lane&15] per 16x16 tile (verified m89 layout)
    #pragma unroll
    for (int i = 0; i < 4; ++i) {
        #pragma unroll
        for (int j = 0; j < 4; ++j) {
            int gc = col0 + wc*64 + j*16 + fr;
            if (gc >= N) continue;
            #pragma unroll
            for (int r = 0; r < 4; ++r) {
                int gr = row0 + wr*64 + i*16 + fq*4 + r;
                float v = acc[i][j][r];
                size_t off = (size_t)bzC * strideC + (size_t)gr * ldc + gc;
                if (mode == 0 || mode == 6) {
                    ((float*)Cv)[off] = v;
                } else if (mode == 1) {
                    ((bf16*)Cv)[off] = __float2bfloat16(v);
                } else if (mode == 2) {
                    ((float*)Cv)[off] = v + res[(size_t)gr * ldc + gc];
                } else if (mode == 3) {
                    float t = v + bias[gc];
                    t = 0.5f * t * (1.0f + erff(t * 0.70710678118654752f));
                    ((bf16*)Cv)[off] = __float2bfloat16(t);
                } else {
                    ((float*)Cv)[off] = v + bias[gc] + res[(size_t)gr * ldc + gc];
                }
            }
        }
    }
}

// ---------------------------------------------------------------------------
// Split-K reduce: dst = sum of nch partial planes (+res)(+bias), float4.
// ---------------------------------------------------------------------------
__global__ __launch_bounds__(256) void red_k(const float* __restrict__ part,
        long long pstride4, int nch, const float* __restrict__ res,
        const float* __restrict__ bias, long long cols4,
        float* __restrict__ dstF, bf16* __restrict__ dstB, long long n4)
{
    long long i = (long long)blockIdx.x * 256 + threadIdx.x;
    long long stride = (long long)gridDim.x * 256;
    for (; i < n4; i += stride) {
        float4 v = ((const float4*)part)[i];
        for (int k = 1; k < nch; ++k) {
            float4 p = ((const float4*)part)[i + k * pstride4];
            v.x += p.x; v.y += p.y; v.z += p.z; v.w += p.w;
        }
        if (res) {
            float4 rr = ((const float4*)res)[i];
            v.x += rr.x; v.y += rr.y; v.z += rr.z; v.w += rr.w;
        }
        if (bias) {
            float4 b = ((const float4*)bias)[i % cols4];
            v.x += b.x; v.y += b.y; v.z += b.z; v.w += b.w;
        }
        if (dstB) {
            ushort4 o;
            bf16 t0 = __float2bfloat16(v.x); o.x = *(unsigned short*)&t0;
            bf16 t1 = __float2bfloat16(v.y); o.y = *(unsigned short*)&t1;
            bf16 t2 = __float2bfloat16(v.z); o.z = *(unsigned short*)&t2;
            bf16 t3 = __float2bfloat16(v.w); o.w = *(unsigned short*)&t3;
            ((ushort4*)dstB)[i] = o;
        } else {
            ((float4*)dstF)[i] = v;
        }
    }
}

// PV split-K reduce with causal chunk-validity: part[head][4][S][128] (kchunk=512)
__global__ __launch_bounds__(128) void pv_red(const float* __restrict__ part,
                                              bf16* __restrict__ ao, int grp)
{
    int r = blockIdx.x, head = blockIdx.y, d = threadIdx.x;
    int nv = ((r >> 7) + 4) >> 2;   // #chunks with kc*512 < ((r/128)+1)*128
    const float* p = part + ((size_t)head * 4) * S_ * VD_ + (size_t)r * VD_ + d;
    float s = 0.f;
    for (int k = 0; k < nv; ++k) s += p[(size_t)k * S_ * VD_];
    ao[(size_t)r * (H_ * VD_) + grp * 1024 + head * VD_ + d] = __float2bfloat16(s);
}

// ---------------------------------------------------------------------------
// Weight transpose + f32->bf16:  in[R,C] f32  ->  out[C,R] bf16
// ---------------------------------------------------------------------------
__global__ __launch_bounds__(256) void transpose_w(const float* __restrict__ in,
                                                   bf16* __restrict__ out, int R, int C)
{
    __shared__ float t[32][33];
    int c0 = blockIdx.x * 32, r0 = blockIdx.y * 32;
    int tx = threadIdx.x, ty = threadIdx.y;
    for (int j = ty; j < 32; j += 8) {
        int r = r0 + j, c = c0 + tx;
        t[j][tx] = (r < R && c < C) ? in[(size_t)r * C + c] : 0.f;
    }
    __syncthreads();
    for (int j = ty; j < 32; j += 8) {
        int c = c0 + j, r = r0 + tx;
        if (c < C && r < R) out[(size_t)c * R + r] = __float2bfloat16(t[tx][j]);
    }
}

// vT[h][d][s] = kv[s][h*256 + 128 + d]
__global__ __launch_bounds__(256) void transpose_v(const bf16* __restrict__ kv,
                                                   bf16* __restrict__ vT)
{
    __shared__ bf16 t[32][33];
    int h = blockIdx.z;
    int d0 = blockIdx.x * 32, s0 = blockIdx.y * 32;
    int tx = threadIdx.x, ty = threadIdx.y;
    for (int j = ty; j < 32; j += 8)
        t[j][tx] = kv[(size_t)(s0 + j) * (H_*256) + h*256 + 128 + d0 + tx];
    __syncthreads();
    for (int j = ty; j < 32; j += 8)
        vT[((size_t)h * VD_ + d0 + j) * S_ + s0 + tx] = t[tx][j];
}

// ---------------------------------------------------------------------------
// RMSNorm: f32 in (strided) -> bf16 out
// ---------------------------------------------------------------------------
__global__ __launch_bounds__(256) void rmsnorm_k(const float* __restrict__ in,
                                                 const float* __restrict__ w,
                                                 bf16* __restrict__ out,
                                                 int cols, int istride, int ostride)
{
    int row = blockIdx.x, tid = threadIdx.x;
    const float* ip = in + (size_t)row * istride;
    bf16* op = out + (size_t)row * ostride;
    float ss = 0.f;
    for (int c = tid; c < cols; c += 256) { float v = ip[c]; ss = fmaf(v, v, ss); }
    for (int o = 32; o > 0; o >>= 1) ss += __shfl_down(ss, o, 64);
    __shared__ float red[4];
    __shared__ float s_sc;
    int wave = tid >> 6, lane = tid & 63;
    if (lane == 0) red[wave] = ss;
    __syncthreads();
    if (tid == 0) s_sc = rsqrtf((red[0]+red[1]+red[2]+red[3]) / (float)cols + EPS_);
    __syncthreads();
    float sc = s_sc;
    for (int c = tid; c < cols; c += 256)
        op[c] = __float2bfloat16(ip[c] * sc * w[c]);
}

// ---------------------------------------------------------------------------
// RoPE helpers
// ---------------------------------------------------------------------------
#define ROPE_LC 0.28782313662425575f

__global__ __launch_bounds__(192) void build_q(const bf16* __restrict__ q,
                                               bf16* __restrict__ qf)
{
    int s = blockIdx.x, h = blockIdx.y, t = threadIdx.x;
    const float scale = 0.07216878364870323f;  // 1/sqrt(192)
    const bf16* src = q + (size_t)s * (H_*QKD_) + h * QKD_;
    bf16* dst = qf + ((size_t)h * S_ + s) * QKD_;
    if (t < NOPE_) {
        dst[t] = __float2bfloat16(__bfloat162float(src[t]) * scale);
    } else {
        int i = (t - NOPE_) & 31;
        bool hi = (t - NOPE_) >= 32;
        float a = __bfloat162float(src[NOPE_ + 2*i]);
        float b = __bfloat162float(src[NOPE_ + 2*i + 1]);
        float inv = __expf(-(float)i * ROPE_LC);
        float f = (float)s * inv, c, sn;
        sincosf(f, &sn, &c);
        float v = hi ? (b * c + a * sn) : (a * c - b * sn);
        dst[t] = __float2bfloat16(v * scale);
    }
}

// kf: nope from kv[s][h*256+d]; roped pe from fused qakva32[s][2048..] (stride 2112)
__global__ __launch_bounds__(192) void build_k(const bf16* __restrict__ kv,
                                               const float* __restrict__ qakva32,
                                               bf16* __restrict__ kf)
{
    int s = blockIdx.x, h = blockIdx.y, t = threadIdx.x;
    const bf16* src = kv + (size_t)s * (H_*256) + h * 256;
    bf16* dst = kf + ((size_t)h * S_ + s) * QKD_;
    if (t < NOPE_) {
        dst[t] = src[t];
    } else {
        int i = (t - NOPE_) & 31;
        bool hi = (t - NOPE_) >= 32;
        const float* pe = qakva32 + (size_t)s * QKVN + (QR_ + KVR_);
        float a = pe[2*i], b = pe[2*i + 1];
        float inv = __expf(-(float)i * ROPE_LC);
        float f = (float)s * inv, c, sn;
        sincosf(f, &sn, &c);
        dst[t] = __float2bfloat16(hi ? (b * c + a * sn) : (a * c - b * sn));
    }
}

// ---------------------------------------------------------------------------
// Causal softmax, register-cached single global pass; zero-pads to 128 boundary.
// ---------------------------------------------------------------------------
__global__ __launch_bounds__(256) void softmax_k(bf16* __restrict__ Sc)
{
    int q = blockIdx.x, h = blockIdx.y;
    bf16* row = Sc + ((size_t)h * S_ + q) * S_;
    int n = q + 1;
    int klim = ((q >> 7) + 1) << 7;
    int tid = threadIdx.x, lane = tid & 63, wave = tid >> 6;
    __shared__ float red[4];
    __shared__ float bc;

    float v[8];
    #pragma unroll
    for (int k = 0; k < 8; ++k) {
        int c = tid + k * 256;
        v[k] = (c < n) ? __bfloat162float(row[c]) : -3.0e38f;
    }
    float mx = v[0];
    #pragma unroll
    for (int k = 1; k < 8; ++k) mx = fmaxf(mx, v[k]);
    for (int o = 32; o > 0; o >>= 1) mx = fmaxf(mx, __shfl_down(mx, o, 64));
    if (lane == 0) red[wave] = mx;
    __syncthreads();
    if (tid == 0) bc = fmaxf(fmaxf(red[0], red[1]), fmaxf(red[2], red[3]));
    __syncthreads();
    float m = bc;
    float sum = 0.f;
    #pragma unroll
    for (int k = 0; k < 8; ++k) {
        int c = tid + k * 256;
        v[k] = (c < n) ? __expf(v[k] - m) : 0.f;
        sum += v[k];
    }
    for (int o = 32; o > 0; o >>= 1) sum += __shfl_down(sum, o, 64);
    __syncthreads();
    if (lane == 0) red[wave] = sum;
    __syncthreads();
    if (tid == 0) bc = 1.0f / (red[0] + red[1] + red[2] + red[3]);
    __syncthreads();
    float inv = bc;
    #pragma unroll
    for (int k = 0; k < 8; ++k) {
        int c = tid + k * 256;
        if (c < klim) row[c] = __float2bfloat16(c < n ? v[k] * inv : 0.f);
    }
}

// ---------------------------------------------------------------------------
static inline void gemm(hipStream_t st, const bf16* A, const bf16* BT, void* C,
                        const float* bias, const float* res,
                        int M, int N, int K, int lda, int ldb, int ldc,
                        long long sA, long long sB, long long sC,
                        int batch, int mode, int causal, int ksplit = 1, int kchunk = 0)
{
    if (kchunk == 0) kchunk = K;
    dim3 g((N + 127) / 128, M / 128, batch * ksplit);
    gemm_k<<<g, 256, 0, st>>>(A, BT, C, bias, res, M, N, K, lda, ldb, ldc,
                              sA, sB, sC, mode, causal, ksplit, kchunk);
}

static inline void transw(hipStream_t st, const float* in, bf16* out, int R, int C)
{
    dim3 g((C + 31) / 32, (R + 31) / 32);
    transpose_w<<<g, dim3(32, 8), 0, st>>>(in, out, R, C);
}

extern "C" void kernel_launch(void* const* d_in, const int* in_sizes, int n_in,
                              void* d_out, int out_size, void* d_ws, size_t ws_size,
                              hipStream_t stream)
{
    const float* x        = (const float*)d_in[0];
    const float* norm1_w  = (const float*)d_in[1];
    const float* q_a_w    = (const float*)d_in[2];
    const float* q_a_ln_w = (const float*)d_in[3];
    const float* q_b_w    = (const float*)d_in[4];
    const float* kv_a_w   = (const float*)d_in[5];
    const float* kv_a_ln_w= (const float*)d_in[6];
    const float* kv_b_w   = (const float*)d_in[7];
    const float* o_w      = (const float*)d_in[8];
    const float* norm2_w  = (const float*)d_in[9];
    const float* ffn_w1   = (const float*)d_in[10];
    const float* ffn_b1   = (const float*)d_in[11];
    const float* ffn_w2   = (const float*)d_in[12];
    const float* ffn_b2   = (const float*)d_in[13];
    float* out = (float*)d_out;

    // ---- workspace layout (~262 MB; split-K partials overlaid on dead regions) ----
    size_t off = 0;
    auto alloc = [&](size_t bytes) -> void* {
        void* p = (char*)d_ws + off;
        off += (bytes + 255) & ~(size_t)255;
        return p;
    };
    bf16*  hs     = (bf16*) alloc((size_t)S_*D_*2);                 //  8.4 MB
    bf16*  wqakvT = (bf16*) alloc((size_t)QKVN*D_*2);               //  8.7 MB
    bf16*  wqbT   = (bf16*) alloc((size_t)(H_*QKD_)*QR_*2);         //  9.4 MB
    bf16*  wkvbT  = (bf16*) alloc((size_t)(H_*(NOPE_+VD_))*KVR_*2); //  4.2 MB
    bf16*  woT    = (bf16*) alloc((size_t)D_*(H_*VD_)*2);           //  8.4 MB
    bf16*  wf1T   = (bf16*) alloc((size_t)(4*D_)*D_*2);             // 33.6 MB
    bf16*  wf2T   = (bf16*) alloc((size_t)D_*(4*D_)*2);             // 33.6 MB
    float* qakva32= (float*)alloc((size_t)S_*QKVN*4);               // 17.3 MB
    bf16*  qln    = (bf16*) alloc((size_t)S_*QR_*2);                //  6.3 MB
    bf16*  kvln   = (bf16*) alloc((size_t)S_*KVR_*2);               //  2.1 MB
    bf16*  qb     = (bf16*) alloc((size_t)S_*H_*QKD_*2);            // 12.6 MB
    bf16*  kvb    = (bf16*) alloc((size_t)S_*H_*(NOPE_+VD_)*2);     // 16.8 MB
    bf16*  qf     = (bf16*) alloc((size_t)H_*S_*QKD_*2);            // 12.6 MB
    bf16*  kf     = (bf16*) alloc((size_t)H_*S_*QKD_*2);            // 12.6 MB
    bf16*  vT     = (bf16*) alloc((size_t)H_*VD_*S_*2);             //  8.4 MB
    bf16*  Sc     = (bf16*) alloc((size_t)8*S_*S_*2);               // 67.1 MB
    // overlays (lifetimes disjoint):
    float* qakvaP = (float*)Sc;       // 3 x 17.3 MB in Sc            (pre-scores)
    float* qbP    = (float*)Sc;       // 2 x 25.2 MB in Sc            (pre-scores)
    float* pvP    = (float*)qakva32;  // 32 x 1.05 MB = 33.6 MB over qakva32+qln+kvln+qb
                                      //   (38.3 MB; all dead during attention)
    float* oP     = (float*)Sc;       // 4 x 16.8 MB = 67.1 MB = Sc exactly
                                      //   (Sc dead after last PV; a1 overwrites only
                                      //    after the o reduce completes)
    float* f2P    = (float*)kvb;      // 3 x 16.8 MB = 50.33 MB = kvb+qf+kf+vT exactly
                                      //   (ao=kvb dead after o gemm; qf/kf/vT dead)
    float* x2     = qakva32;          // f32 residual, written post-attention
    bf16*  h2     = qb;               // post-attention rmsnorm output
    bf16*  ao     = kvb;              // attn out bf16 [S][2048] (kvb dead after builds)
    bf16*  a1     = Sc;               // ffn1 activation 33.6 MB (after o reduce)

    // ---- weight transposes (qa+kva fused along N) ----
    transw(stream, q_a_w,  wqakvT,                    D_,  QR_);
    transw(stream, kv_a_w, wqakvT + (size_t)QR_ * D_, D_,  KVR_+ROPE_);
    transw(stream, q_b_w,  wqbT,  QR_, H_*QKD_);
    transw(stream, kv_b_w, wkvbT, KVR_, H_*(NOPE_+VD_));
    transw(stream, o_w,    woT,   H_*VD_, D_);
    transw(stream, ffn_w1, wf1T,  D_,  4*D_);
    transw(stream, ffn_w2, wf2T,  4*D_, D_);

    // ---- pre-attention pipeline ----
    rmsnorm_k<<<S_, 256, 0, stream>>>(x, norm1_w, hs, D_, D_, D_);

    // fused qa+kva: split-K 3 (816 blocks = 3.2/CU) -> partials -> f32 qakva32
    gemm(stream, hs, wqakvT, qakvaP, nullptr, nullptr, S_, QKVN, D_, D_, D_, QKVN,
         0, 0, (long long)S_*QKVN, 1, 6, 0, 3, 768);
    red_k<<<1024, 256, 0, stream>>>(qakvaP, (long long)S_*QKVN/4, 3, nullptr, nullptr, 1,
                                    qakva32, nullptr, (long long)S_*QKVN/4);

    rmsnorm_k<<<S_, 256, 0, stream>>>(qakva32, q_a_ln_w, qln, QR_, QKVN, QR_);
    gemm(stream, qln, wqbT, qbP, nullptr, nullptr, S_, H_*QKD_, QR_, QR_, QR_, H_*QKD_,
         0, 0, (long long)S_*(H_*QKD_), 1, 6, 0, 2, 768);
    red_k<<<1024, 256, 0, stream>>>(qbP, (long long)S_*(H_*QKD_)/4, 2, nullptr, nullptr, 1,
                                    nullptr, qb, (long long)S_*(H_*QKD_)/4);

    rmsnorm_k<<<S_, 256, 0, stream>>>(qakva32 + QR_, kv_a_ln_w, kvln, KVR_, QKVN, KVR_);
    gemm(stream, kvln, wkvbT, kvb, nullptr, nullptr, S_, H_*(NOPE_+VD_), KVR_,
         KVR_, KVR_, H_*(NOPE_+VD_), 0, 0, 0, 1, 1, 0);

    build_q<<<dim3(S_, H_), 192, 0, stream>>>(qb, qf);
    build_k<<<dim3(S_, H_), 192, 0, stream>>>(kvb, qakva32, kf);
    transpose_v<<<dim3(VD_/32, S_/32, H_), dim3(32, 8), 0, stream>>>(kvb, vT);

    // ---- attention: 2 groups of 8 heads; PV split-K 4 with partials ----
    for (int g = 0; g < 2; ++g) {
        const bf16* qfg = qf + (size_t)g * 8 * S_ * QKD_;
        const bf16* kfg = kf + (size_t)g * 8 * S_ * QKD_;
        const bf16* vTg = vT + (size_t)g * 8 * VD_ * S_;
        gemm(stream, qfg, kfg, Sc, nullptr, nullptr,
             S_, S_, QKD_, QKD_, QKD_, S_,
             (long long)S_*QKD_, (long long)S_*QKD_, (long long)S_*S_, 8, 1, 1);
        softmax_k<<<dim3(S_, 8), 256, 0, stream>>>(Sc);
        gemm(stream, Sc, vTg, pvP, nullptr, nullptr,
             S_, VD_, S_, S_, S_, VD_,
             (long long)S_*S_, (long long)VD_*S_, (long long)S_*VD_, 8, 6, 2, 4, 512);
        pv_red<<<dim3(S_, 8), 128, 0, stream>>>(pvP, ao, g);
    }

    // ---- o-projection + residual: split-K 4 (1024 blocks = 4/CU); reduce adds x ----
    gemm(stream, ao, woT, oP, nullptr, nullptr, S_, D_, H_*VD_, H_*VD_, H_*VD_, D_,
         0, 0, (long long)S_*D_, 1, 6, 0, 4, 512);
    red_k<<<1024, 256, 0, stream>>>(oP, (long long)S_*D_/4, 4, x, nullptr, 1,
                                    x2, nullptr, (long long)S_*D_/4);

    // ---- FFN ----
    rmsnorm_k<<<S_, 256, 0, stream>>>(x2, norm2_w, h2, D_, D_, D_);
    gemm(stream, h2, wf1T, a1, ffn_b1, nullptr, S_, 4*D_, D_, D_, D_, 4*D_,
         0, 0, 0, 1, 3, 0);
    // ffn2: split-K 3 (768 blocks = 3/CU), kchunk 2752 (86/86/84 iters)
    gemm(stream, a1, wf2T, f2P, nullptr, nullptr, S_, D_, 4*D_, 4*D_, 4*D_, D_,
         0, 0, (long long)S_*D_, 1, 6, 0, 3, 2752);
    red_k<<<1024, 256, 0, stream>>>(f2P, (long long)S_*D_/4, 3, x2, ffn_b2, D_/4,
                                    out, nullptr, (long long)S_*D_/4);
}

// Round 7
// 970.751 us; speedup vs baseline: 1.1694x; 1.1694x over previous
//
#include <hip/hip_runtime.h>
#include <hip/hip_bf16.h>

typedef __hip_bfloat16 bf16;
using bf16x8 = __attribute__((ext_vector_type(8))) __bf16;
using f32x4  = __attribute__((ext_vector_type(4))) float;

#define S_   2048
#define D_   2048
#define H_   16
#define QR_  1536
#define KVR_ 512
#define NOPE_ 128
#define ROPE_ 64
#define VD_  128
#define QKD_ 192
#define EPS_ 1e-5f
#define QKVN 2112   // QR_ + KVR_ + ROPE_ (fused qa+kva output width)

// async global->LDS, 16B per lane; LDS dest = wave-uniform base + lane*16
#define GLDS16(g, l) \
    __builtin_amdgcn_global_load_lds((const __attribute__((address_space(1))) void*)(g), \
                                     (__attribute__((address_space(3))) void*)(l), 16, 0, 0)

// Fine-grained pipeline barrier: wait only the OLDEST stage's 4 loads
// (8 outstanding -> 4), then s_barrier. Never vmcnt(0) mid-loop — the
// in-flight prefetch for stage it+1/it+2 crosses the barrier (AITER pattern).
#define PIPE_WAIT4 asm volatile("s_waitcnt vmcnt(4)\n\ts_barrier" ::: "memory")
#define PIPE_WAIT0 asm volatile("s_waitcnt vmcnt(0)\n\ts_barrier" ::: "memory")

// ---------------------------------------------------------------------------
// bf16 MFMA GEMM: C[M,N] = A[M,K] @ B[K,N], B given as BT[N,K].
// 256 thr = 4 waves; tile 128x128; wave does 64x64 (4x4 of 16x16x32 bf16).
// 3-stage software-pipelined K-loop: prefetch distance 2 (~800 cyc) covers
// HBM latency; vmcnt(4) barriers keep younger loads in flight. Split-K via
// private f32 partial planes (mode 6) + reduce kernel. No atomics.
// mode: 0=f32 store, 1=bf16 store, 2=f32 +res, 3=bf16 gelu(x+bias),
//       4=f32 +bias+res, 6=f32 partial store (split-K)
// causal: 0=none, 1=skip tiles above diagonal (scores), 2=K limited to diag (PV)
// ---------------------------------------------------------------------------
__global__ __launch_bounds__(256) void gemm_k(
    const bf16* __restrict__ A, const bf16* __restrict__ BT, void* __restrict__ Cv,
    const float* __restrict__ bias, const float* __restrict__ res,
    int M, int N, int K, int lda, int ldb, int ldc,
    long long strideA, long long strideB, long long strideC,
    int mode, int causal, int ksplit, int kchunk)
{
    int bn = blockIdx.x, bm = blockIdx.y;
    int bzC = blockIdx.z;                 // C-plane index (batch*ksplit packed)
    int bz = bzC, kc = 0;
    if (ksplit > 1) { kc = bzC % ksplit; bz = bzC / ksplit; }
    if (causal == 1 && bn > bm) return;
    A  += (size_t)bz * strideA;
    BT += (size_t)bz * strideB;

    int k_end = K;
    if (causal == 2) { int kl = (bm + 1) * 128; if (kl < k_end) k_end = kl; }
    int k_begin = kc * kchunk;
    if (k_begin + kchunk < k_end) k_end = k_begin + kchunk;
    if (k_begin >= k_end) return;          // block-uniform: whole block skips barriers
    int nIter = (k_end - k_begin) >> 5;    // K multiples of 32 everywhere here

    __shared__ bf16 sA[3 * 128 * 32];      // 3-stage ring, 24 KB
    __shared__ bf16 sB[3 * 128 * 32];      // 24 KB

    int tid  = threadIdx.x;
    int lane = tid & 63, wave = tid >> 6;
    int wr = wave >> 1, wc = wave & 1;     // wave's 64x64 quadrant
    int fr = lane & 15, fq = lane >> 4;    // fragment row / k-quad

    int row0 = bm * 128, col0 = bn * 128;

    // staging: wave w covers rows [w*16, w*16+16) and +64; lane L -> row w*16+L/4, k-off (L&3)*8
    int srow = wave * 16 + (lane >> 2);
    int sko  = (lane & 3) * 8;
    const bf16* ga0 = A + (size_t)(row0 + srow) * lda + sko;
    const bf16* ga1 = ga0 + (size_t)64 * lda;
    int bn0 = col0 + srow;      if (bn0 > N - 1) bn0 = N - 1;   // clamp (cols >= N discarded)
    int bn1 = col0 + srow + 64; if (bn1 > N - 1) bn1 = N - 1;
    const bf16* gb0 = BT + (size_t)bn0 * ldb + sko;
    const bf16* gb1 = BT + (size_t)bn1 * ldb + sko;
    bf16* lA0 = &sA[(wave * 16) * 32];
    bf16* lA1 = &sA[(64 + wave * 16) * 32];
    bf16* lB0 = &sB[(wave * 16) * 32];
    bf16* lB1 = &sB[(64 + wave * 16) * 32];

#define STAGE(ofs, k0) do {                  \
        GLDS16(ga0 + (k0), lA0 + (ofs));     \
        GLDS16(ga1 + (k0), lA1 + (ofs));     \
        GLDS16(gb0 + (k0), lB0 + (ofs));     \
        GLDS16(gb1 + (k0), lB1 + (ofs));     \
    } while (0)

    f32x4 acc[4][4] = {};

#define COMPUTE(ofs) do {                                                           \
        bf16x8 af[4], bv[4];                                                        \
        _Pragma("unroll")                                                           \
        for (int i = 0; i < 4; ++i)                                                 \
            af[i] = *(const bf16x8*)&sA[(ofs) + (wr*64 + i*16 + fr)*32 + fq*8];     \
        _Pragma("unroll")                                                           \
        for (int j = 0; j < 4; ++j)                                                 \
            bv[j] = *(const bf16x8*)&sB[(ofs) + (wc*64 + j*16 + fr)*32 + fq*8];     \
        _Pragma("unroll")                                                           \
        for (int i = 0; i < 4; ++i)                                                 \
            _Pragma("unroll")                                                       \
            for (int j = 0; j < 4; ++j)                                             \
                acc[i][j] = __builtin_amdgcn_mfma_f32_16x16x32_bf16(af[i], bv[j], acc[i][j], 0, 0, 0); \
    } while (0)

    // prologue: stages 0 and 1 in flight (8 outstanding loads per wave)
    STAGE(0, k_begin);
    if (nIter > 1) STAGE(4096, k_begin + 32);

    int curo = 0, pfo = 8192;   // LDS ring offsets: compute stage it, prefetch it+2
    int it = 0;
    for (; it < nIter - 1; ++it) {
        PIPE_WAIT4;                                   // oldest stage landed; younger stay in flight
        if (it + 2 < nIter) STAGE(pfo, k_begin + (it + 2) * 32);
        COMPUTE(curo);
        curo += 4096; if (curo == 12288) curo = 0;
        pfo  += 4096; if (pfo  == 12288) pfo  = 0;
    }
    PIPE_WAIT0;                                       // final stage
    COMPUTE(curo);
#undef STAGE
#undef COMPUTE

    // epilogue: D[row=(lane>>4)*4+r][col=lane&15] per 16x16 tile (verified m89 layout)
    #pragma unroll
    for (int i = 0; i < 4; ++i) {
        #pragma unroll
        for (int j = 0; j < 4; ++j) {
            int gc = col0 + wc*64 + j*16 + fr;
            if (gc >= N) continue;
            #pragma unroll
            for (int r = 0; r < 4; ++r) {
                int gr = row0 + wr*64 + i*16 + fq*4 + r;
                float v = acc[i][j][r];
                size_t off = (size_t)bzC * strideC + (size_t)gr * ldc + gc;
                if (mode == 0 || mode == 6) {
                    ((float*)Cv)[off] = v;
                } else if (mode == 1) {
                    ((bf16*)Cv)[off] = __float2bfloat16(v);
                } else if (mode == 2) {
                    ((float*)Cv)[off] = v + res[(size_t)gr * ldc + gc];
                } else if (mode == 3) {
                    float t = v + bias[gc];
                    t = 0.5f * t * (1.0f + erff(t * 0.70710678118654752f));
                    ((bf16*)Cv)[off] = __float2bfloat16(t);
                } else {
                    ((float*)Cv)[off] = v + bias[gc] + res[(size_t)gr * ldc + gc];
                }
            }
        }
    }
}

// ---------------------------------------------------------------------------
// Split-K reduce: dst = sum of nch partial planes (+res)(+bias), float4.
// ---------------------------------------------------------------------------
__global__ __launch_bounds__(256) void red_k(const float* __restrict__ part,
        long long pstride4, int nch, const float* __restrict__ res,
        const float* __restrict__ bias, long long cols4,
        float* __restrict__ dstF, bf16* __restrict__ dstB, long long n4)
{
    long long i = (long long)blockIdx.x * 256 + threadIdx.x;
    long long stride = (long long)gridDim.x * 256;
    for (; i < n4; i += stride) {
        float4 v = ((const float4*)part)[i];
        for (int k = 1; k < nch; ++k) {
            float4 p = ((const float4*)part)[i + k * pstride4];
            v.x += p.x; v.y += p.y; v.z += p.z; v.w += p.w;
        }
        if (res) {
            float4 rr = ((const float4*)res)[i];
            v.x += rr.x; v.y += rr.y; v.z += rr.z; v.w += rr.w;
        }
        if (bias) {
            float4 b = ((const float4*)bias)[i % cols4];
            v.x += b.x; v.y += b.y; v.z += b.z; v.w += b.w;
        }
        if (dstB) {
            ushort4 o;
            bf16 t0 = __float2bfloat16(v.x); o.x = *(unsigned short*)&t0;
            bf16 t1 = __float2bfloat16(v.y); o.y = *(unsigned short*)&t1;
            bf16 t2 = __float2bfloat16(v.z); o.z = *(unsigned short*)&t2;
            bf16 t3 = __float2bfloat16(v.w); o.w = *(unsigned short*)&t3;
            ((ushort4*)dstB)[i] = o;
        } else {
            ((float4*)dstF)[i] = v;
        }
    }
}

// PV split-K reduce with causal chunk-validity: part[head][4][S][128] (kchunk=512)
__global__ __launch_bounds__(128) void pv_red(const float* __restrict__ part,
                                              bf16* __restrict__ ao, int grp)
{
    int r = blockIdx.x, head = blockIdx.y, d = threadIdx.x;
    int nv = ((r >> 7) + 4) >> 2;   // #chunks with kc*512 < ((r/128)+1)*128
    const float* p = part + ((size_t)head * 4) * S_ * VD_ + (size_t)r * VD_ + d;
    float s = 0.f;
    for (int k = 0; k < nv; ++k) s += p[(size_t)k * S_ * VD_];
    ao[(size_t)r * (H_ * VD_) + grp * 1024 + head * VD_ + d] = __float2bfloat16(s);
}

// ---------------------------------------------------------------------------
// Weight transpose + f32->bf16:  in[R,C] f32  ->  out[C,R] bf16
// ---------------------------------------------------------------------------
__global__ __launch_bounds__(256) void transpose_w(const float* __restrict__ in,
                                                   bf16* __restrict__ out, int R, int C)
{
    __shared__ float t[32][33];
    int c0 = blockIdx.x * 32, r0 = blockIdx.y * 32;
    int tx = threadIdx.x, ty = threadIdx.y;
    for (int j = ty; j < 32; j += 8) {
        int r = r0 + j, c = c0 + tx;
        t[j][tx] = (r < R && c < C) ? in[(size_t)r * C + c] : 0.f;
    }
    __syncthreads();
    for (int j = ty; j < 32; j += 8) {
        int c = c0 + j, r = r0 + tx;
        if (c < C && r < R) out[(size_t)c * R + r] = __float2bfloat16(t[tx][j]);
    }
}

// vT[h][d][s] = kv[s][h*256 + 128 + d]
__global__ __launch_bounds__(256) void transpose_v(const bf16* __restrict__ kv,
                                                   bf16* __restrict__ vT)
{
    __shared__ bf16 t[32][33];
    int h = blockIdx.z;
    int d0 = blockIdx.x * 32, s0 = blockIdx.y * 32;
    int tx = threadIdx.x, ty = threadIdx.y;
    for (int j = ty; j < 32; j += 8)
        t[j][tx] = kv[(size_t)(s0 + j) * (H_*256) + h*256 + 128 + d0 + tx];
    __syncthreads();
    for (int j = ty; j < 32; j += 8)
        vT[((size_t)h * VD_ + d0 + j) * S_ + s0 + tx] = t[tx][j];
}

// ---------------------------------------------------------------------------
// RMSNorm: f32 in (strided) -> bf16 out
// ---------------------------------------------------------------------------
__global__ __launch_bounds__(256) void rmsnorm_k(const float* __restrict__ in,
                                                 const float* __restrict__ w,
                                                 bf16* __restrict__ out,
                                                 int cols, int istride, int ostride)
{
    int row = blockIdx.x, tid = threadIdx.x;
    const float* ip = in + (size_t)row * istride;
    bf16* op = out + (size_t)row * ostride;
    float ss = 0.f;
    for (int c = tid; c < cols; c += 256) { float v = ip[c]; ss = fmaf(v, v, ss); }
    for (int o = 32; o > 0; o >>= 1) ss += __shfl_down(ss, o, 64);
    __shared__ float red[4];
    __shared__ float s_sc;
    int wave = tid >> 6, lane = tid & 63;
    if (lane == 0) red[wave] = ss;
    __syncthreads();
    if (tid == 0) s_sc = rsqrtf((red[0]+red[1]+red[2]+red[3]) / (float)cols + EPS_);
    __syncthreads();
    float sc = s_sc;
    for (int c = tid; c < cols; c += 256)
        op[c] = __float2bfloat16(ip[c] * sc * w[c]);
}

// ---------------------------------------------------------------------------
// RoPE helpers
// ---------------------------------------------------------------------------
#define ROPE_LC 0.28782313662425575f

__global__ __launch_bounds__(192) void build_q(const bf16* __restrict__ q,
                                               bf16* __restrict__ qf)
{
    int s = blockIdx.x, h = blockIdx.y, t = threadIdx.x;
    const float scale = 0.07216878364870323f;  // 1/sqrt(192)
    const bf16* src = q + (size_t)s * (H_*QKD_) + h * QKD_;
    bf16* dst = qf + ((size_t)h * S_ + s) * QKD_;
    if (t < NOPE_) {
        dst[t] = __float2bfloat16(__bfloat162float(src[t]) * scale);
    } else {
        int i = (t - NOPE_) & 31;
        bool hi = (t - NOPE_) >= 32;
        float a = __bfloat162float(src[NOPE_ + 2*i]);
        float b = __bfloat162float(src[NOPE_ + 2*i + 1]);
        float inv = __expf(-(float)i * ROPE_LC);
        float f = (float)s * inv, c, sn;
        sincosf(f, &sn, &c);
        float v = hi ? (b * c + a * sn) : (a * c - b * sn);
        dst[t] = __float2bfloat16(v * scale);
    }
}

// kf: nope from kv[s][h*256+d]; roped pe from fused qakva32[s][2048..] (stride 2112)
__global__ __launch_bounds__(192) void build_k(const bf16* __restrict__ kv,
                                               const float* __restrict__ qakva32,
                                               bf16* __restrict__ kf)
{
    int s = blockIdx.x, h = blockIdx.y, t = threadIdx.x;
    const bf16* src = kv + (size_t)s * (H_*256) + h * 256;
    bf16* dst = kf + ((size_t)h * S_ + s) * QKD_;
    if (t < NOPE_) {
        dst[t] = src[t];
    } else {
        int i = (t - NOPE_) & 31;
        bool hi = (t - NOPE_) >= 32;
        const float* pe = qakva32 + (size_t)s * QKVN + (QR_ + KVR_);
        float a = pe[2*i], b = pe[2*i + 1];
        float inv = __expf(-(float)i * ROPE_LC);
        float f = (float)s * inv, c, sn;
        sincosf(f, &sn, &c);
        dst[t] = __float2bfloat16(hi ? (b * c + a * sn) : (a * c - b * sn));
    }
}

// ---------------------------------------------------------------------------
// Causal softmax, register-cached single global pass; zero-pads to 128 boundary.
// ---------------------------------------------------------------------------
__global__ __launch_bounds__(256) void softmax_k(bf16* __restrict__ Sc)
{
    int q = blockIdx.x, h = blockIdx.y;
    bf16* row = Sc + ((size_t)h * S_ + q) * S_;
    int n = q + 1;
    int klim = ((q >> 7) + 1) << 7;
    int tid = threadIdx.x, lane = tid & 63, wave = tid >> 6;
    __shared__ float red[4];
    __shared__ float bc;

    float v[8];
    #pragma unroll
    for (int k = 0; k < 8; ++k) {
        int c = tid + k * 256;
        v[k] = (c < n) ? __bfloat162float(row[c]) : -3.0e38f;
    }
    float mx = v[0];
    #pragma unroll
    for (int k = 1; k < 8; ++k) mx = fmaxf(mx, v[k]);
    for (int o = 32; o > 0; o >>= 1) mx = fmaxf(mx, __shfl_down(mx, o, 64));
    if (lane == 0) red[wave] = mx;
    __syncthreads();
    if (tid == 0) bc = fmaxf(fmaxf(red[0], red[1]), fmaxf(red[2], red[3]));
    __syncthreads();
    float m = bc;
    float sum = 0.f;
    #pragma unroll
    for (int k = 0; k < 8; ++k) {
        int c = tid + k * 256;
        v[k] = (c < n) ? __expf(v[k] - m) : 0.f;
        sum += v[k];
    }
    for (int o = 32; o > 0; o >>= 1) sum += __shfl_down(sum, o, 64);
    __syncthreads();
    if (lane == 0) red[wave] = sum;
    __syncthreads();
    if (tid == 0) bc = 1.0f / (red[0] + red[1] + red[2] + red[3]);
    __syncthreads();
    float inv = bc;
    #pragma unroll
    for (int k = 0; k < 8; ++k) {
        int c = tid + k * 256;
        if (c < klim) row[c] = __float2bfloat16(c < n ? v[k] * inv : 0.f);
    }
}

// ---------------------------------------------------------------------------
static inline void gemm(hipStream_t st, const bf16* A, const bf16* BT, void* C,
                        const float* bias, const float* res,
                        int M, int N, int K, int lda, int ldb, int ldc,
                        long long sA, long long sB, long long sC,
                        int batch, int mode, int causal, int ksplit = 1, int kchunk = 0)
{
    if (kchunk == 0) kchunk = K;
    dim3 g((N + 127) / 128, M / 128, batch * ksplit);
    gemm_k<<<g, 256, 0, st>>>(A, BT, C, bias, res, M, N, K, lda, ldb, ldc,
                              sA, sB, sC, mode, causal, ksplit, kchunk);
}

static inline void transw(hipStream_t st, const float* in, bf16* out, int R, int C)
{
    dim3 g((C + 31) / 32, (R + 31) / 32);
    transpose_w<<<g, dim3(32, 8), 0, st>>>(in, out, R, C);
}

extern "C" void kernel_launch(void* const* d_in, const int* in_sizes, int n_in,
                              void* d_out, int out_size, void* d_ws, size_t ws_size,
                              hipStream_t stream)
{
    const float* x        = (const float*)d_in[0];
    const float* norm1_w  = (const float*)d_in[1];
    const float* q_a_w    = (const float*)d_in[2];
    const float* q_a_ln_w = (const float*)d_in[3];
    const float* q_b_w    = (const float*)d_in[4];
    const float* kv_a_w   = (const float*)d_in[5];
    const float* kv_a_ln_w= (const float*)d_in[6];
    const float* kv_b_w   = (const float*)d_in[7];
    const float* o_w      = (const float*)d_in[8];
    const float* norm2_w  = (const float*)d_in[9];
    const float* ffn_w1   = (const float*)d_in[10];
    const float* ffn_b1   = (const float*)d_in[11];
    const float* ffn_w2   = (const float*)d_in[12];
    const float* ffn_b2   = (const float*)d_in[13];
    float* out = (float*)d_out;

    // ---- workspace layout (R5 proven; split-K partials overlaid on dead regions) ----
    size_t off = 0;
    auto alloc = [&](size_t bytes) -> void* {
        void* p = (char*)d_ws + off;
        off += (bytes + 255) & ~(size_t)255;
        return p;
    };
    bf16*  hs     = (bf16*) alloc((size_t)S_*D_*2);                 //  8.4 MB
    bf16*  wqakvT = (bf16*) alloc((size_t)QKVN*D_*2);               //  8.7 MB
    bf16*  wqbT   = (bf16*) alloc((size_t)(H_*QKD_)*QR_*2);         //  9.4 MB
    bf16*  wkvbT  = (bf16*) alloc((size_t)(H_*(NOPE_+VD_))*KVR_*2); //  4.2 MB
    bf16*  woT    = (bf16*) alloc((size_t)D_*(H_*VD_)*2);           //  8.4 MB
    bf16*  wf1T   = (bf16*) alloc((size_t)(4*D_)*D_*2);             // 33.6 MB
    bf16*  wf2T   = (bf16*) alloc((size_t)D_*(4*D_)*2);             // 33.6 MB
    float* qakva32= (float*)alloc((size_t)S_*QKVN*4);               // 17.3 MB
    bf16*  qln    = (bf16*) alloc((size_t)S_*QR_*2);                //  6.3 MB
    bf16*  kvln   = (bf16*) alloc((size_t)S_*KVR_*2);               //  2.1 MB
    bf16*  qb     = (bf16*) alloc((size_t)S_*H_*QKD_*2);            // 12.6 MB
    bf16*  kvb    = (bf16*) alloc((size_t)S_*H_*(NOPE_+VD_)*2);     // 16.8 MB
    bf16*  qf     = (bf16*) alloc((size_t)H_*S_*QKD_*2);            // 12.6 MB
    bf16*  kf     = (bf16*) alloc((size_t)H_*S_*QKD_*2);            // 12.6 MB
    bf16*  vT     = (bf16*) alloc((size_t)H_*VD_*S_*2);             //  8.4 MB
    bf16*  Sc     = (bf16*) alloc((size_t)8*S_*S_*2);               // 67.1 MB
    // overlays (lifetimes disjoint):
    float* qakvaP = (float*)Sc;       // 2 x 17.3 MB in Sc            (pre-scores)
    float* qbP    = (float*)Sc;       // 2 x 25.2 MB in Sc            (pre-scores)
    float* pvP    = (float*)qakva32;  // 32 x 1.05 MB = 33.6 MB over qakva32+qln+kvln+qb
                                      //   (38.3 MB; all dead during attention)
    float* oP     = (float*)qf;       // 2 x 16.8 MB over qf+kf+vT    (dead post-attention)
    float* f2P    = (float*)qf;       // 2 x 16.8 MB                  (after o reduce)
    float* x2     = qakva32;          // f32 residual, written post-attention
    bf16*  h2     = qb;               // post-attention rmsnorm output
    bf16*  ao     = kvb;              // attn out bf16 [S][2048] (kvb dead after builds)
    bf16*  a1     = Sc;               // ffn1 activation 33.6 MB (Sc dead post-attention)

    // ---- weight transposes (qa+kva fused along N) ----
    transw(stream, q_a_w,  wqakvT,                    D_,  QR_);
    transw(stream, kv_a_w, wqakvT + (size_t)QR_ * D_, D_,  KVR_+ROPE_);
    transw(stream, q_b_w,  wqbT,  QR_, H_*QKD_);
    transw(stream, kv_b_w, wkvbT, KVR_, H_*(NOPE_+VD_));
    transw(stream, o_w,    woT,   H_*VD_, D_);
    transw(stream, ffn_w1, wf1T,  D_,  4*D_);
    transw(stream, ffn_w2, wf2T,  4*D_, D_);

    // ---- pre-attention pipeline ----
    rmsnorm_k<<<S_, 256, 0, stream>>>(x, norm1_w, hs, D_, D_, D_);

    // fused qa+kva: split-K 2 -> partials (Sc overlay) -> f32 qakva32
    gemm(stream, hs, wqakvT, qakvaP, nullptr, nullptr, S_, QKVN, D_, D_, D_, QKVN,
         0, 0, (long long)S_*QKVN, 1, 6, 0, 2, 1024);
    red_k<<<1024, 256, 0, stream>>>(qakvaP, (long long)S_*QKVN/4, 2, nullptr, nullptr, 1,
                                    qakva32, nullptr, (long long)S_*QKVN/4);

    rmsnorm_k<<<S_, 256, 0, stream>>>(qakva32, q_a_ln_w, qln, QR_, QKVN, QR_);
    gemm(stream, qln, wqbT, qbP, nullptr, nullptr, S_, H_*QKD_, QR_, QR_, QR_, H_*QKD_,
         0, 0, (long long)S_*(H_*QKD_), 1, 6, 0, 2, 768);
    red_k<<<1024, 256, 0, stream>>>(qbP, (long long)S_*(H_*QKD_)/4, 2, nullptr, nullptr, 1,
                                    nullptr, qb, (long long)S_*(H_*QKD_)/4);

    rmsnorm_k<<<S_, 256, 0, stream>>>(qakva32 + QR_, kv_a_ln_w, kvln, KVR_, QKVN, KVR_);
    gemm(stream, kvln, wkvbT, kvb, nullptr, nullptr, S_, H_*(NOPE_+VD_), KVR_,
         KVR_, KVR_, H_*(NOPE_+VD_), 0, 0, 0, 1, 1, 0);

    build_q<<<dim3(S_, H_), 192, 0, stream>>>(qb, qf);
    build_k<<<dim3(S_, H_), 192, 0, stream>>>(kvb, qakva32, kf);
    transpose_v<<<dim3(VD_/32, S_/32, H_), dim3(32, 8), 0, stream>>>(kvb, vT);

    // ---- attention: 2 groups of 8 heads; PV split-K 4 with partials ----
    for (int g = 0; g < 2; ++g) {
        const bf16* qfg = qf + (size_t)g * 8 * S_ * QKD_;
        const bf16* kfg = kf + (size_t)g * 8 * S_ * QKD_;
        const bf16* vTg = vT + (size_t)g * 8 * VD_ * S_;
        gemm(stream, qfg, kfg, Sc, nullptr, nullptr,
             S_, S_, QKD_, QKD_, QKD_, S_,
             (long long)S_*QKD_, (long long)S_*QKD_, (long long)S_*S_, 8, 1, 1);
        softmax_k<<<dim3(S_, 8), 256, 0, stream>>>(Sc);
        gemm(stream, Sc, vTg, pvP, nullptr, nullptr,
             S_, VD_, S_, S_, S_, VD_,
             (long long)S_*S_, (long long)VD_*S_, (long long)S_*VD_, 8, 6, 2, 4, 512);
        pv_red<<<dim3(S_, 8), 128, 0, stream>>>(pvP, ao, g);
    }

    // ---- o-projection + residual: split-K 2 partials; reduce adds x ----
    gemm(stream, ao, woT, oP, nullptr, nullptr, S_, D_, H_*VD_, H_*VD_, H_*VD_, D_,
         0, 0, (long long)S_*D_, 1, 6, 0, 2, 1024);
    red_k<<<1024, 256, 0, stream>>>(oP, (long long)S_*D_/4, 2, x, nullptr, 1,
                                    x2, nullptr, (long long)S_*D_/4);

    // ---- FFN ----
    rmsnorm_k<<<S_, 256, 0, stream>>>(x2, norm2_w, h2, D_, D_, D_);
    gemm(stream, h2, wf1T, a1, ffn_b1, nullptr, S_, 4*D_, D_, D_, D_, 4*D_,
         0, 0, 0, 1, 3, 0);
    gemm(stream, a1, wf2T, f2P, nullptr, nullptr, S_, D_, 4*D_, 4*D_, 4*D_, D_,
         0, 0, (long long)S_*D_, 1, 6, 0, 2, 4096);
    red_k<<<1024, 256, 0, stream>>>(f2P, (long long)S_*D_/4, 2, x2, ffn_b2, D_/4,
                                    out, nullptr, (long long)S_*D_/4);
}